// Round 6
// baseline (156.637 us; speedup 1.0000x reference)
//
#include <hip/hip_runtime.h>

// Problem constants (from reference)
#define ZD_ 64
#define PD_ 16
#define DH_ 128
#define SW_STRIDE 132      // s_w row stride (words): 132*4 % 16 == 0 (b128-aligned),
                           // lane=row b128 reads hit the uniform 8-words/bank floor
#define SE_STRIDE 73       // s_exe row stride (73 coprime-ish with 32: scatter writes 2/bank)

// ---------------------------------------------------------------------------
// K0: hid[64][128] = relu([z_all | pde] @ W1^T + b1)   (unchanged, verified)
// ---------------------------------------------------------------------------
__global__ void hid_kernel(const float* __restrict__ z_all,
                           const float* __restrict__ W1,
                           const float* __restrict__ b1,
                           const float* __restrict__ pde,
                           float* __restrict__ hid) {
    int gid = blockIdx.x * 256 + threadIdx.x;   // 8192 outputs
    int r = gid >> 7;                            // z row (0..63)
    int d = gid & 127;                           // hidden unit
    const float* w = W1 + d * (ZD_ + PD_);
    const float* z = z_all + r * ZD_;
    float acc = b1[d];
    #pragma unroll 8
    for (int c = 0; c < ZD_; ++c) acc += z[c] * w[c];
    #pragma unroll
    for (int c = 0; c < PD_; ++c) acc += pde[c] * w[ZD_ + c];
    hid[gid] = fmaxf(acc, 0.0f);
}

// ---------------------------------------------------------------------------
// K1 (fused): exe GEMM + outer product in one kernel.
//   exe[o][i][kk] = hid[hk] . W2[n] + b2[n],  n = ob*576 + ib*9 + kk
//   out[o][i][k][l] = exe[o][i][k] * unet[o][i][l]
//   o = h*64+ob ; i = kb*64+ib ; hk = h*8+kb
// Block = 72 consecutive n (= 8 COMPLETE i-rows: 72 = 8*9, 8*72 = 576 so
// blocks never straddle ob). Stage the contiguous 36KB W2 slab coalesced
// into LDS. Wave w computes hk in [w*16,w*16+16): hid rows wave-uniform ->
// s_load broadcasts; lane = n (first 64 n, 16 accs); the 8-n tail is
// redistributed: lane handles (hk = hkbase+(lane>>3)*2+j2, n = 64+(lane&7))
// for j2 in {0,1} with per-lane hid vector loads (L1-hot) -- no exec-masked
// waste. exe goes through s_exe; output phase is a flat fully-coalesced
// b32 store pass (verified /81,/9 magic-div math from R3's outer).
// Grid: 512 blocks x 256 threads; LDS 75136 B -> exactly 2 blocks/CU.
// ---------------------------------------------------------------------------
__global__ __launch_bounds__(256) void fused_kernel(
        const float* __restrict__ hid,
        const float* __restrict__ W2,
        const float* __restrict__ b2,
        const float* __restrict__ unet,
        float* __restrict__ out) {
    __shared__ __align__(16) float s_w[72 * SW_STRIDE];   // 38016 B
    __shared__ float s_exe[64 * SE_STRIDE];               // 18688 B
    __shared__ float s_unet[64 * 72];                     // 18432 B

    const int tid = threadIdx.x;
    const int blk = blockIdx.x;
    const int ob  = blk >> 3;            // 0..63
    const int ib0 = (blk & 7) * 8;       // 0..56
    const int n0  = blk * 72;

    // ---- stage W2 rows [n0, n0+72): 2304 float4, fully coalesced ----
    const float4* g4 = reinterpret_cast<const float4*>(W2 + (size_t)n0 * DH_);
    #pragma unroll
    for (int j = 0; j < 9; ++j) {
        int g   = j * 256 + tid;         // 0..2303
        int row = g >> 5;
        int k4  = g & 31;
        *reinterpret_cast<float4*>(&s_w[row * SW_STRIDE + k4 * 4]) = g4[g];
    }
    // ---- stage unet: 64 segs (seg = h*8+kb) x 72 floats ----
    #pragma unroll
    for (int j = 0; j < 18; ++j) {
        int t   = j * 256 + tid;         // 0..4607
        int seg = t / 72;
        int off = t - seg * 72;
        int h = seg >> 3, kb = seg & 7;
        size_t gb = ((size_t)(h * 64 + ob) * 512 + kb * 64 + ib0) * 9;
        s_unet[t] = unet[gb + off];
    }
    __syncthreads();

    // ---- compute: wave w -> hk in [w*16, w*16+16) ----
    const int wave   = __builtin_amdgcn_readfirstlane(tid >> 6);
    const int lane   = tid & 63;
    const int hkbase = wave * 16;
    const float* hbase = hid + (size_t)hkbase * DH_;   // wave-uniform

    float acc[16];
    {
        float bias = b2[n0 + lane];
        #pragma unroll
        for (int j = 0; j < 16; ++j) acc[j] = bias;
    }
    const int tj = (lane >> 3) * 2;      // tail hk offset: 0,2,...,14
    const int tn = 64 + (lane & 7);      // tail n: 64..71
    float accT[2];
    {
        float biasT = b2[n0 + tn];
        accT[0] = biasT; accT[1] = biasT;
    }

    const float* wrow = s_w + lane * SW_STRIDE;
    const float* trow = s_w + tn * SW_STRIDE;
    #pragma unroll 4
    for (int c = 0; c < 32; ++c) {
        const int k0 = c * 4;
        float4 wv = *reinterpret_cast<const float4*>(wrow + k0);   // ds_read_b128
        #pragma unroll
        for (int j = 0; j < 16; ++j) {
            float4 hv = *reinterpret_cast<const float4*>(hbase + j * DH_ + k0); // s_load
            acc[j] += hv.x * wv.x + hv.y * wv.y + hv.z * wv.z + hv.w * wv.w;
        }
        float4 tv = *reinterpret_cast<const float4*>(trow + k0);   // 8-row broadcast
        #pragma unroll
        for (int j2 = 0; j2 < 2; ++j2) {
            float4 hv = *reinterpret_cast<const float4*>(
                hid + (size_t)(hkbase + tj + j2) * DH_ + k0);      // vector load, L1-hot
            accT[j2] += hv.x * tv.x + hv.y * tv.y + hv.z * tv.z + hv.w * tv.w;
        }
    }

    // ---- scatter exe to LDS: s_exe[hk][nn] ----
    #pragma unroll
    for (int j = 0; j < 16; ++j)
        s_exe[(hkbase + j) * SE_STRIDE + lane] = acc[j];
    s_exe[(hkbase + tj + 0) * SE_STRIDE + tn] = accT[0];
    s_exe[(hkbase + tj + 1) * SE_STRIDE + tn] = accT[1];
    __syncthreads();

    // ---- fused outer product, flat coalesced b32 stores ----
    // g = seg*648 + r ; r = ibl*81 + k*9 + l ; nn = ibl*9 + k
    for (int g = tid; g < 64 * 648; g += 256) {
        int seg = g / 648;
        int r   = g - seg * 648;
        int ibl = r / 81;
        int rr  = r - ibl * 81;
        int k   = rr / 9;
        int l   = rr - k * 9;
        float v = s_exe[seg * SE_STRIDE + ibl * 9 + k]
                * s_unet[seg * 72 + ibl * 9 + l];
        int h = seg >> 3, kb = seg & 7;
        size_t gb = ((size_t)(h * 64 + ob) * 512 + kb * 64 + ib0) * 81;
        out[gb + r] = v;                 // consecutive lanes -> consecutive addrs
    }
}

// ---------------------------------------------------------------------------
extern "C" void kernel_launch(void* const* d_in, const int* in_sizes, int n_in,
                              void* d_out, int out_size, void* d_ws, size_t ws_size,
                              hipStream_t stream) {
    const float* z_all = (const float*)d_in[0];  // [64,64]
    const float* W1    = (const float*)d_in[1];  // [128,80]
    const float* b1    = (const float*)d_in[2];  // [128]
    const float* W2    = (const float*)d_in[3];  // [36864,128]
    const float* b2    = (const float*)d_in[4];  // [36864]
    const float* unet  = (const float*)d_in[5];  // [512,512,9]
    const float* pde   = (const float*)d_in[6];  // [16]
    float* out = (float*)d_out;                  // [512,512,9,9]

    float* hid = (float*)d_ws;                   // 8192 floats (fully rewritten)

    hid_kernel<<<32, 256, 0, stream>>>(z_all, W1, b1, pde, hid);
    fused_kernel<<<512, 256, 0, stream>>>(hid, W2, b2, unet, out);
}